// Round 2
// baseline (127.945 us; speedup 1.0000x reference)
//
#include <hip/hip_runtime.h>
#include <math.h>

#define B_    2
#define C_    64
#define N_    20000
#define K_    16
#define COUT_ 64
#define TN1   64
#define NB1   ((N_ + TN1 - 1) / TN1)   // 313
#define TN2   16
#define NB2   (N_ / TN2)               // 1250 (exact, no tail)
#define NCH   2                        // channel chunks: 32 ch = 64 B rows

typedef unsigned int   u32;
typedef unsigned short u16;

static __device__ __forceinline__ u16 f2bf(float f) {
    union { float f; u32 u; } v; v.f = f;
    u32 r = (v.u + 0x7FFFu + ((v.u >> 16) & 1u)) >> 16;  // RNE
    return (u16)r;
}
static __device__ __forceinline__ float uasf(u32 u) {
    union { u32 u; float f; } v; v.u = u; return v.f;
}

// ---------------------------------------------------------------------------
// Stage 1: per-node GEMM. z = (W1-W2)x + b, y = W2 x -> bf16 tables.
// Chunked layout [chunk][b][n][32ch] (64 B rows): stage2 pins each
// (b,chunk) slice (2.56 MB z+y) to one XCD's 4 MiB L2.
// Core compute unchanged (proven: LDS weights, named accumulators).
// ---------------------------------------------------------------------------
__global__ __launch_bounds__(256)
void stage1(const float* __restrict__ x, const float* __restrict__ W,
            const float* __restrict__ bias,
            u16* __restrict__ zbuf, u16* __restrict__ ybuf) {
    __shared__ float xt[64][68];    // [c][n_local], rows 16B-aligned
    __shared__ float wc[64][130];   // [c][2*o+{0,1}] = (w1-w2, w2)

    const int bi   = blockIdx.x;
    const int b    = bi / NB1;
    const int n0   = (bi % NB1) * TN1;
    const int t    = threadIdx.x;
    const int lane = t & 63;        // = output channel o
    const int w    = t >> 6;

    // ---- stage weights (coalesced): 64o x 64c ----
    #pragma unroll
    for (int r = 0; r < 16; ++r) {
        int flat = r * 256 + t;
        int o = flat >> 6, c = flat & 63;
        float w1 = W[o * 128 + c];
        float w2 = W[o * 128 + 64 + c];
        wc[c][2 * o]     = w1 - w2;
        wc[c][2 * o + 1] = w2;
    }
    // ---- stage x tile [c][n] via float4 (coalesced) ----
    const float* xb = x + (size_t)b * C_ * N_;
    #pragma unroll
    for (int r = 0; r < 4; ++r) {
        int flat = r * 256 + t;
        int c = flat >> 4, ng = (flat & 15) * 4;
        int n = n0 + ng;
        float4 v;
        if (n + 3 < N_) {
            v = *(const float4*)&xb[c * N_ + n];
        } else {
            v.x = (n     < N_) ? xb[c * N_ + n    ] : 0.0f;
            v.y = (n + 1 < N_) ? xb[c * N_ + n + 1] : 0.0f;
            v.z = (n + 2 < N_) ? xb[c * N_ + n + 2] : 0.0f;
            v.w = (n + 3 < N_) ? xb[c * N_ + n + 3] : 0.0f;
        }
        *(float4*)&xt[c][ng] = v;
    }
    const float bo = bias[lane];
    __syncthreads();

    // ---- wave computes 16 nodes, all accumulators NAMED float4 ----
    const int nb = w * 16;
    float4 z0 = {bo,bo,bo,bo}, z1 = z0, z2 = z0, z3 = z0;
    float4 y0 = {0,0,0,0},     y1 = y0, y2 = y0, y3 = y0;

#define FMA4(ZR, YR, XV) \
    ZR.x = fmaf(wv.x, XV.x, ZR.x);  YR.x = fmaf(wv.y, XV.x, YR.x); \
    ZR.y = fmaf(wv.x, XV.y, ZR.y);  YR.y = fmaf(wv.y, XV.y, YR.y); \
    ZR.z = fmaf(wv.x, XV.z, ZR.z);  YR.z = fmaf(wv.y, XV.z, YR.z); \
    ZR.w = fmaf(wv.x, XV.w, ZR.w);  YR.w = fmaf(wv.y, XV.w, YR.w);

    #pragma unroll 2
    for (int c = 0; c < 64; ++c) {
        float2 wv = *(const float2*)&wc[c][2 * lane];   // conflict-free
        float4 xa = *(const float4*)&xt[c][nb];         // uniform broadcasts
        float4 xv1 = *(const float4*)&xt[c][nb + 4];
        float4 xv2 = *(const float4*)&xt[c][nb + 8];
        float4 xv3 = *(const float4*)&xt[c][nb + 12];
        FMA4(z0, y0, xa)
        FMA4(z1, y1, xv1)
        FMA4(z2, y2, xv2)
        FMA4(z3, y3, xv3)
    }
#undef FMA4

    {
        // chunked store: chunk = o>>5, within-chunk channel = o&31
        const size_t chb = ((size_t)(lane >> 5) * B_ + b) * N_;
        auto st = [&](int i, float zv, float yv) {
            int n = n0 + nb + i;
            if (n < N_) {
                size_t off = (chb + n) * 32 + (lane & 31);  // 64 B coalesced
                zbuf[off] = f2bf(zv);
                ybuf[off] = f2bf(yv);
            }
        };
        st(0,  z0.x, y0.x); st(1,  z0.y, y0.y); st(2,  z0.z, y0.z); st(3,  z0.w, y0.w);
        st(4,  z1.x, y1.x); st(5,  z1.y, y1.y); st(6,  z1.z, y1.z); st(7,  z1.w, y1.w);
        st(8,  z2.x, y2.x); st(9,  z2.y, y2.y); st(10, z2.z, y2.z); st(11, z2.w, y2.w);
        st(12, z3.x, y3.x); st(13, z3.y, y3.y); st(14, z3.z, y3.z); st(15, z3.w, y3.w);
    }
}

// ---------------------------------------------------------------------------
// Stage 2: gather + relu + suppress + k-max, channel-chunked with
// SPATIAL XCD pinning. blockIdx -> XCD is round-robin (bid % 8), so the
// (b,ch) phase lives in the LOW 3 bits: phase p = bid&3 runs only on
// XCDs {p, p+4}. Each XCD's L2 then holds exactly its 2.56 MB z+y slice
// for the whole kernel (vs 10.24 MB thrash before). Edge-index loads are
// nontemporal (read once per XCD -> don't evict table lines); out stores
// nontemporal. Phase A (edge prep) fused per tile, recomputed per chunk
// (cheaper than an ebuf round trip + third launch: round-1 post-mortem).
// ---------------------------------------------------------------------------
__global__ __launch_bounds__(256)
void stage2(const int* __restrict__ ei, const float* __restrict__ pos,
            const u16* __restrict__ zbuf, const u16* __restrict__ ybuf,
            float* __restrict__ out) {
    __shared__ uint2 esl[TN2][17];       // pad 17 -> low-conflict reads
    __shared__ float tile[TN2][34];      // [n_local][32 ch]

    const int bid  = blockIdx.x;         // q*8 + x8
    const int x8   = bid & 7;
    const int p    = x8 & 3;             // phase
    const int b    = p >> 1;
    const int ch   = p & 1;
    const int tl   = (bid >> 3) * 2 + (x8 >> 2);   // 0..1249
    const int n0   = tl * TN2;
    const int t    = threadIdx.x;
    const int nl   = t >> 4;             // node 0..15
    const int ks   = (t >> 2) & 3;       // k-group 0..3 (k = 4i+ks)
    const int cq   = t & 3;              // 16 B chunk = 8 channels

    // ---- Phase A: edge prep for this tile's 256 edges (1/thread) ----
    {
        const int    idx = n0 * K_ + t;                      // coalesced
        const int*   e0  = ei + (size_t)b * N_ * K_;
        const int*   e1  = ei + ((size_t)B_ + b) * N_ * K_;
        const float* pb  = pos + (size_t)b * 3 * N_;
        int i0 = __builtin_nontemporal_load(&e0[idx]);
        int i1 = __builtin_nontemporal_load(&e1[idx]);
        float dx = pb[i0]          - pb[i1];
        float dy = pb[N_ + i0]     - pb[N_ + i1];
        float dz = pb[2 * N_ + i0] - pb[2 * N_ + i1];
        float dis = sqrtf(dx * dx + dy * dy + dz * dz);
        float s = 2.0f / (1.0f + __expf(dis));               // 2*sigmoid(-dis)
        esl[t >> 4][t & 15] = make_uint2((u32)i0 | ((u32)i1 << 16),
                                         __float_as_uint(s));
    }
    __syncthreads();

    const u16* zb = zbuf + ((size_t)ch * B_ + b) * N_ * 32;
    const u16* yb = ybuf + ((size_t)ch * B_ + b) * N_ * 32;

    float4 ma = {0,0,0,0}, mb = {0,0,0,0};   // 8 channel maxima (named)

#define COMB(ZW, YW, MLO, MHI) { \
    float zl = uasf((ZW) << 16), zh = uasf((ZW) & 0xFFFF0000u); \
    float yl = uasf((YW) << 16), yh = uasf((YW) & 0xFFFF0000u); \
    MLO = fmaxf(MLO, fmaxf(zl + yl, 0.0f) * s); \
    MHI = fmaxf(MHI, fmaxf(zh + yh, 0.0f) * s); }

    #pragma unroll
    for (int i = 0; i < 4; ++i) {
        uint2 e = esl[nl][4 * i + ks];   // 4-lane broadcast
        int   i0 = (int)(e.x & 0xFFFFu);
        int   i1 = (int)(e.x >> 16);
        float s  = uasf(e.y);
        uint4 z4 = *((const uint4*)(zb + ((size_t)i1 << 5)) + cq);  // 16 B
        uint4 y4 = *((const uint4*)(yb + ((size_t)i0 << 5)) + cq);
        COMB(z4.x, y4.x, ma.x, ma.y)
        COMB(z4.y, y4.y, ma.z, ma.w)
        COMB(z4.z, y4.z, mb.x, mb.y)
        COMB(z4.w, y4.w, mb.z, mb.w)
    }
#undef COMB

    // ---- merge the four k-groups (lane bits 2..3 = ks) ----
    ma.x = fmaxf(ma.x, __shfl_xor(ma.x, 4));
    ma.y = fmaxf(ma.y, __shfl_xor(ma.y, 4));
    ma.z = fmaxf(ma.z, __shfl_xor(ma.z, 4));
    ma.w = fmaxf(ma.w, __shfl_xor(ma.w, 4));
    mb.x = fmaxf(mb.x, __shfl_xor(mb.x, 4));
    mb.y = fmaxf(mb.y, __shfl_xor(mb.y, 4));
    mb.z = fmaxf(mb.z, __shfl_xor(mb.z, 4));
    mb.w = fmaxf(mb.w, __shfl_xor(mb.w, 4));
    ma.x = fmaxf(ma.x, __shfl_xor(ma.x, 8));
    ma.y = fmaxf(ma.y, __shfl_xor(ma.y, 8));
    ma.z = fmaxf(ma.z, __shfl_xor(ma.z, 8));
    ma.w = fmaxf(ma.w, __shfl_xor(ma.w, 8));
    mb.x = fmaxf(mb.x, __shfl_xor(mb.x, 8));
    mb.y = fmaxf(mb.y, __shfl_xor(mb.y, 8));
    mb.z = fmaxf(mb.z, __shfl_xor(mb.z, 8));
    mb.w = fmaxf(mb.w, __shfl_xor(mb.w, 8));

    if (ks == 0) {
        int cb = cq * 8;
        *(float2*)&tile[nl][cb]     = make_float2(ma.x, ma.y);
        *(float2*)&tile[nl][cb + 2] = make_float2(ma.z, ma.w);
        *(float2*)&tile[nl][cb + 4] = make_float2(mb.x, mb.y);
        *(float2*)&tile[nl][cb + 6] = make_float2(mb.z, mb.w);
    }
    __syncthreads();

    // ---- coalesced writeback: 32 o x 16 n (nontemporal: keep tables hot) ----
    #pragma unroll
    for (int r = 0; r < 2; ++r) {
        int flat = r * 256 + t;
        int o = flat >> 4, n2 = flat & 15;
        __builtin_nontemporal_store(tile[n2][o],
            &out[((size_t)b * COUT_ + ch * 32 + o) * N_ + n0 + n2]);
    }
}

// ---------------------------------------------------------------------------
extern "C" void kernel_launch(void* const* d_in, const int* in_sizes, int n_in,
                              void* d_out, int out_size, void* d_ws, size_t ws_size,
                              hipStream_t stream) {
    const float* x    = (const float*)d_in[0];   // [B, C, N, 1]
    const int*   ei   = (const int*)  d_in[1];   // [2, B, N, K]
    const float* pos  = (const float*)d_in[2];   // [B, 3, N, 1]
    const float* W    = (const float*)d_in[3];   // [COUT, 2C]
    const float* bias = (const float*)d_in[4];   // [COUT]
    float*       out  = (float*)d_out;           // [B, COUT, N, 1]

    const size_t tabElems = (size_t)NCH * B_ * N_ * 32;      // 2.56M u16
    u16* zbuf = (u16*)d_ws;                                  // 5.12 MB
    u16* ybuf = zbuf + tabElems;                             // 5.12 MB

    hipLaunchKernelGGL(stage1, dim3(B_ * NB1), dim3(256), 0, stream,
                       x, W, bias, zbuf, ybuf);
    // grid = 625 * 8: bid = q*8 + x8; XCD (bid%8) determines (b,ch) phase
    hipLaunchKernelGGL(stage2, dim3(B_ * NCH * NB2), dim3(256), 0, stream,
                       ei, pos, zbuf, ybuf, out);
}

// Round 3
// 109.328 us; speedup vs baseline: 1.1703x; 1.1703x over previous
//
#include <hip/hip_runtime.h>
#include <math.h>

#define B_    2
#define C_    64
#define N_    20000
#define K_    16
#define COUT_ 64
#define TN1   64
#define NB1   ((N_ + TN1 - 1) / TN1)   // 313
#define TN2   32
#define NB2   (N_ / TN2)               // 625 (exact, no tail)

typedef unsigned int   u32;
typedef unsigned short u16;

static __device__ __forceinline__ u16 f2bf(float f) {
    union { float f; u32 u; } v; v.f = f;
    u32 r = (v.u + 0x7FFFu + ((v.u >> 16) & 1u)) >> 16;  // RNE
    return (u16)r;
}
static __device__ __forceinline__ float uasf(u32 u) {
    union { u32 u; float f; } v; v.u = u; return v.f;
}

// ---------------------------------------------------------------------------
// Stage 1 (round-0 proven): per-node GEMM. z = (W1-W2)x + b, y = W2 x ->
// bf16 tables [b][n][64ch] (128 B rows = full L2 line useful per gather).
// ---------------------------------------------------------------------------
__global__ __launch_bounds__(256)
void stage1(const float* __restrict__ x, const float* __restrict__ W,
            const float* __restrict__ bias,
            u16* __restrict__ zbuf, u16* __restrict__ ybuf) {
    __shared__ float xt[64][68];    // [c][n_local], rows 16B-aligned
    __shared__ float wc[64][130];   // [c][2*o+{0,1}] = (w1-w2, w2)

    const int bi   = blockIdx.x;
    const int b    = bi / NB1;
    const int n0   = (bi % NB1) * TN1;
    const int t    = threadIdx.x;
    const int lane = t & 63;        // = output channel o
    const int w    = t >> 6;

    // ---- stage weights (coalesced): 64o x 64c ----
    #pragma unroll
    for (int r = 0; r < 16; ++r) {
        int flat = r * 256 + t;
        int o = flat >> 6, c = flat & 63;
        float w1 = W[o * 128 + c];
        float w2 = W[o * 128 + 64 + c];
        wc[c][2 * o]     = w1 - w2;
        wc[c][2 * o + 1] = w2;
    }
    // ---- stage x tile [c][n] via float4 (coalesced) ----
    const float* xb = x + (size_t)b * C_ * N_;
    #pragma unroll
    for (int r = 0; r < 4; ++r) {
        int flat = r * 256 + t;
        int c = flat >> 4, ng = (flat & 15) * 4;
        int n = n0 + ng;
        float4 v;
        if (n + 3 < N_) {
            v = *(const float4*)&xb[c * N_ + n];
        } else {
            v.x = (n     < N_) ? xb[c * N_ + n    ] : 0.0f;
            v.y = (n + 1 < N_) ? xb[c * N_ + n + 1] : 0.0f;
            v.z = (n + 2 < N_) ? xb[c * N_ + n + 2] : 0.0f;
            v.w = (n + 3 < N_) ? xb[c * N_ + n + 3] : 0.0f;
        }
        *(float4*)&xt[c][ng] = v;
    }
    const float bo = bias[lane];
    __syncthreads();

    // ---- wave computes 16 nodes, all accumulators NAMED float4 ----
    const int nb = w * 16;
    float4 z0 = {bo,bo,bo,bo}, z1 = z0, z2 = z0, z3 = z0;
    float4 y0 = {0,0,0,0},     y1 = y0, y2 = y0, y3 = y0;

#define FMA4(ZR, YR, XV) \
    ZR.x = fmaf(wv.x, XV.x, ZR.x);  YR.x = fmaf(wv.y, XV.x, YR.x); \
    ZR.y = fmaf(wv.x, XV.y, ZR.y);  YR.y = fmaf(wv.y, XV.y, YR.y); \
    ZR.z = fmaf(wv.x, XV.z, ZR.z);  YR.z = fmaf(wv.y, XV.z, YR.z); \
    ZR.w = fmaf(wv.x, XV.w, ZR.w);  YR.w = fmaf(wv.y, XV.w, YR.w);

    #pragma unroll 2
    for (int c = 0; c < 64; ++c) {
        float2 wv = *(const float2*)&wc[c][2 * lane];   // conflict-free
        float4 xa = *(const float4*)&xt[c][nb];         // uniform broadcasts
        float4 xv1 = *(const float4*)&xt[c][nb + 4];
        float4 xv2 = *(const float4*)&xt[c][nb + 8];
        float4 xv3 = *(const float4*)&xt[c][nb + 12];
        FMA4(z0, y0, xa)
        FMA4(z1, y1, xv1)
        FMA4(z2, y2, xv2)
        FMA4(z3, y3, xv3)
    }
#undef FMA4

    {
        const size_t rowb = (size_t)b * N_;
        auto st = [&](int i, float zv, float yv) {
            int n = n0 + nb + i;
            if (n < N_) {
                size_t off = (rowb + n) * 64 + lane;    // 128 B coalesced
                zbuf[off] = f2bf(zv);
                ybuf[off] = f2bf(yv);
            }
        };
        st(0,  z0.x, y0.x); st(1,  z0.y, y0.y); st(2,  z0.z, y0.z); st(3,  z0.w, y0.w);
        st(4,  z1.x, y1.x); st(5,  z1.y, y1.y); st(6,  z1.z, y1.z); st(7,  z1.w, y1.w);
        st(8,  z2.x, y2.x); st(9,  z2.y, y2.y); st(10, z2.z, y2.z); st(11, z2.w, y2.w);
        st(12, z3.x, y3.x); st(13, z3.y, y3.y); st(14, z3.z, y3.z); st(15, z3.w, y3.w);
    }
}

// ---------------------------------------------------------------------------
// Stage 2: MLP-maximized gather + relu + suppress + k-max.
// Thread = (node nl 0..31, cq 0..7 = 16 B channel chunk). Each thread owns
// ALL 16 k's of its node: 32 independent 16 B gathers fully unrolled
// (4x the in-flight loads of the old k-split scheme), k-max is thread-
// local (no shuffles). 8 cq lanes cover a full 128 B row contiguously ->
// every fetched L2/L3 line is 100% useful. One barrier after edge prep,
// one before the transpose writeback.
// ---------------------------------------------------------------------------
__global__ __launch_bounds__(256)
void stage2(const int* __restrict__ ei, const float* __restrict__ pos,
            const u16* __restrict__ zbuf, const u16* __restrict__ ybuf,
            float* __restrict__ out) {
    __shared__ uint2 esl[TN2][17];       // pad 17 -> conflict-free reads
    __shared__ float tile[TN2][65];      // [n_local][o], pad 65

    const int bi  = blockIdx.x;
    const int b   = bi / NB2;
    const int n0  = (bi % NB2) * TN2;
    const int t   = threadIdx.x;
    const int nl  = t >> 3;              // node 0..31
    const int cq  = t & 7;               // 16 B chunk = 8 channels

    // ---- Phase A: edge prep, 512 edges, 2 per thread (coalesced int2) ----
    {
        const int    e2  = 2 * t;                            // 0..510
        const int    idx = n0 * K_ + e2;
        const int*   e0  = ei + (size_t)b * N_ * K_;
        const int*   e1  = ei + ((size_t)B_ + b) * N_ * K_;
        const float* pb  = pos + (size_t)b * 3 * N_;
        int2 i0p = *(const int2*)&e0[idx];
        int2 i1p = *(const int2*)&e1[idx];
        float dx0 = pb[i0p.x]          - pb[i1p.x];
        float dy0 = pb[N_ + i0p.x]     - pb[N_ + i1p.x];
        float dz0 = pb[2 * N_ + i0p.x] - pb[2 * N_ + i1p.x];
        float dx1 = pb[i0p.y]          - pb[i1p.y];
        float dy1 = pb[N_ + i0p.y]     - pb[N_ + i1p.y];
        float dz1 = pb[2 * N_ + i0p.y] - pb[2 * N_ + i1p.y];
        float d0 = sqrtf(dx0 * dx0 + dy0 * dy0 + dz0 * dz0);
        float d1 = sqrtf(dx1 * dx1 + dy1 * dy1 + dz1 * dz1);
        float s0 = 2.0f / (1.0f + __expf(d0));               // 2*sigmoid(-d)
        float s1 = 2.0f / (1.0f + __expf(d1));
        const int na = e2 >> 4, ka = e2 & 15;
        esl[na][ka]     = make_uint2((u32)i0p.x | ((u32)i1p.x << 16),
                                     __float_as_uint(s0));
        esl[na][ka + 1] = make_uint2((u32)i0p.y | ((u32)i1p.y << 16),
                                     __float_as_uint(s1));
    }
    __syncthreads();

    const uint4* zb = (const uint4*)(zbuf + (size_t)b * N_ * 64) + cq;
    const uint4* yb = (const uint4*)(ybuf + (size_t)b * N_ * 64) + cq;

    float4 ma = {0,0,0,0}, mb = {0,0,0,0};   // 8 channel maxima (named)

#define COMB(ZW, YW, MLO, MHI) { \
    float zl = uasf((ZW) << 16), zh = uasf((ZW) & 0xFFFF0000u); \
    float yl = uasf((YW) << 16), yh = uasf((YW) & 0xFFFF0000u); \
    MLO = fmaxf(MLO, fmaxf(zl + yl, 0.0f) * s); \
    MHI = fmaxf(MHI, fmaxf(zh + yh, 0.0f) * s); }

    #pragma unroll
    for (int k = 0; k < 16; ++k) {
        uint2 e = esl[nl][k];            // 8-lane broadcast, conflict-free
        int   i0 = (int)(e.x & 0xFFFFu);
        int   i1 = (int)(e.x >> 16);
        float s  = uasf(e.y);
        uint4 z4 = zb[(size_t)i1 << 3];  // rows are 8 uint4s (128 B)
        uint4 y4 = yb[(size_t)i0 << 3];
        COMB(z4.x, y4.x, ma.x, ma.y)
        COMB(z4.y, y4.y, ma.z, ma.w)
        COMB(z4.z, y4.z, mb.x, mb.y)
        COMB(z4.w, y4.w, mb.z, mb.w)
    }
#undef COMB

    {
        int cb = cq * 8;
        *(float2*)&tile[nl][cb]     = make_float2(ma.x, ma.y);
        *(float2*)&tile[nl][cb + 2] = make_float2(ma.z, ma.w);
        *(float2*)&tile[nl][cb + 4] = make_float2(mb.x, mb.y);
        *(float2*)&tile[nl][cb + 6] = make_float2(mb.z, mb.w);
    }
    __syncthreads();

    // ---- coalesced writeback: 64 o x 32 n (nontemporal: keep tables hot) ----
    #pragma unroll
    for (int r = 0; r < 8; ++r) {
        int flat = r * 256 + t;
        int o = flat >> 5, n2 = flat & 31;
        __builtin_nontemporal_store(tile[n2][o],
            &out[((size_t)b * COUT_ + o) * N_ + n0 + n2]);
    }
}

// ---------------------------------------------------------------------------
extern "C" void kernel_launch(void* const* d_in, const int* in_sizes, int n_in,
                              void* d_out, int out_size, void* d_ws, size_t ws_size,
                              hipStream_t stream) {
    const float* x    = (const float*)d_in[0];   // [B, C, N, 1]
    const int*   ei   = (const int*)  d_in[1];   // [2, B, N, K]
    const float* pos  = (const float*)d_in[2];   // [B, 3, N, 1]
    const float* W    = (const float*)d_in[3];   // [COUT, 2C]
    const float* bias = (const float*)d_in[4];   // [COUT]
    float*       out  = (float*)d_out;           // [B, COUT, N, 1]

    const size_t tabElems = (size_t)B_ * N_ * 64;            // 2.56M u16
    u16* zbuf = (u16*)d_ws;                                  // 5.12 MB
    u16* ybuf = zbuf + tabElems;                             // 5.12 MB

    hipLaunchKernelGGL(stage1, dim3(B_ * NB1), dim3(256), 0, stream,
                       x, W, bias, zbuf, ybuf);
    hipLaunchKernelGGL(stage2, dim3(B_ * NB2), dim3(256), 0, stream,
                       ei, pos, zbuf, ybuf, out);
}